// Round 12
// baseline (811.269 us; speedup 1.0000x reference)
//
#include <hip/hip_runtime.h>
#include <hip/hip_bf16.h>
#include <cmath>

#define TT 512
#define BB 32
#define EE 256
#define HH 128
#define KCRF 12
#define NEGF (-10000.0f)

// ---------------------------------------------------------------------------
// K12 fused: 256 WGs x 512 threads.
//   WG 0..63   : the round-3 anchor LSTM scan (proven 471us), plus a 9-lane
//                flag-burst wait once per 16 steps.
//   WG 64..255 : XG producers. Item = (t-pair, 256-col slab), emitted in
//                priority order interleaving (low t, cols 0..511) for the
//                forward chains and (high t, cols 512..1023) for reverse.
//                Tile = proven k1 64x128 micro-structure, doubled to 512
//                threads (two column halves share the A-stage).
// Flags: int flags[pair][half] counts finished slabs (target 2). Reset to 0
// by hipMemsetAsync before launch each call (d_ws is not re-poisoned between
// replays). Producer: __syncthreads (drains vmcnt for ALL threads' stores)
// -> tid0 __threadfence (L2 writeback, cross-XCD) -> device atomicAdd.
// Consumer: device atomicAdd(.,0) poll; all 256 WGs provably co-resident
// (8 waves, 48KB LDS -> >=3 WGs/CU capacity) so spinning cannot deadlock.
// ---------------------------------------------------------------------------
__global__ __launch_bounds__(512)
void k12_fused(const int* __restrict__ sent, const float* __restrict__ embed,
               const float* __restrict__ Wf, const float* __restrict__ bfv,
               const float* __restrict__ Wr, const float* __restrict__ brv,
               const float* __restrict__ Whf, const float* __restrict__ Whr,
               const float* __restrict__ h0, const float* __restrict__ c0,
               float* XG, float* __restrict__ HS, int* flags)
{
  __shared__ __align__(16) float As[64][36];
  __shared__ __align__(16) float Bs[256][36];
  __shared__ __align__(16) float hs[128];
  __shared__ float gs[512];

  const int wg = blockIdx.x;
  const int tid = threadIdx.x;

  if (wg >= 64) {
    // ------------------------- producers -------------------------
    const int sub = tid >> 8;           // 0/1: which 128-col half of the slab
    const int t256 = tid & 255;
    const int ty = t256 >> 4, tx = t256 & 15;
    for (int item = wg - 64; item < 1024; item += 192) {
      const int g = item >> 2, q = item & 3;
      const int pair = (q < 2) ? g : (255 - g);   // t-pair: rows pair*64..+63
      const int half = q >> 1;                    // 0: cols 0-511, 1: 512-1023
      const int n0 = (q & 1) * 256 + half * 512;  // slab base (256 cols)
      const int m0 = pair * 64;
      const int colbase = n0 + sub * 128;

      float acc[4][8];
#pragma unroll
      for (int i = 0; i < 4; ++i)
#pragma unroll
        for (int j = 0; j < 8; ++j) acc[i][j] = 0.f;

      for (int k0 = 0; k0 < 256; k0 += 32) {
        { // A: 64x32 gathered embed rows, 1 float4/thread
          int row = tid >> 3, c4 = (tid & 7) << 2;
          int R = m0 + row, t = R >> 5, b = R & 31;
          *(float4*)&As[row][c4] =
              *(const float4*)(embed + (long)sent[b * TT + t] * 256 + k0 + c4);
        }
#pragma unroll
        for (int r = 0; r < 4; ++r) {   // B: 256x32 of W_cat
          int idx = tid + r * 512, row = idx >> 3, c4 = (idx & 7) << 2;
          int col = n0 + row;
          const float* src = (col < 512) ? (Wf + (long)col * 256)
                                         : (Wr + (long)(col - 512) * 256);
          *(float4*)&Bs[row][c4] = *(const float4*)(src + k0 + c4);
        }
        __syncthreads();
#pragma unroll
        for (int kk = 0; kk < 32; ++kk) {
          float a[4], bv[8];
#pragma unroll
          for (int i = 0; i < 4; ++i) a[i] = As[ty * 4 + i][kk];
#pragma unroll
          for (int j = 0; j < 8; ++j) bv[j] = Bs[sub * 128 + tx + 16 * j][kk];
#pragma unroll
          for (int i = 0; i < 4; ++i)
#pragma unroll
            for (int j = 0; j < 8; ++j) acc[i][j] = fmaf(a[i], bv[j], acc[i][j]);
        }
        __syncthreads();
      }
#pragma unroll
      for (int i = 0; i < 4; ++i) {
        const long R = m0 + ty * 4 + i;
#pragma unroll
        for (int j = 0; j < 8; ++j) {
          const int col = colbase + tx + 16 * j;
          const float bias = (col < 512) ? bfv[col] : brv[col - 512];
          XG[R * 1024 + col] = acc[i][j] + bias;
        }
      }
      __syncthreads();   // drains vmcnt(0): all threads' XG stores complete
      if (tid == 0) { __threadfence(); atomicAdd(&flags[pair * 2 + half], 1); }
    }
  } else {
    // ----------------- scan (round-3 anchor + burst waits) -----------------
    const int dir = wg >> 5;
    const int b = wg & 31;
    const int j = tid;
    const float* Wh = dir ? Whr : Whf;

    float4 w[32];
#pragma unroll
    for (int i = 0; i < 32; ++i)
      w[i] = *(const float4*)(Wh + (long)j * 128 + i * 4);

    float c = 0.f;
    if (j < 128) {
      hs[j] = h0[(dir * 32 + b) * 128 + j];
      c = c0[(dir * 32 + b) * 128 + j];
    }
    __syncthreads();

    const int t0 = dir ? (TT - 1) : 0;
    const long stepoff = dir ? -32768 : 32768;   // 32*1024 floats per t
    const float* xp = XG + ((long)t0 * 32 + b) * 1024 + dir * 512 + j;
    const int gate = j >> 7;   // 0=i 1=f 2=g 3=o

    // burst wait for pairs covering steps s..s+15 (incl. prefetch t at s+16):
    // lanes 0..8 poll 9 consecutive pairs in their direction's order.
    {
      if (tid < 9) {
        int p0 = dir ? ((TT - 1) >> 1) : 0;
        int p = dir ? (p0 - tid) : (p0 + tid);
        p = p < 0 ? 0 : (p > 255 ? 255 : p);
        while (atomicAdd(&flags[p * 2 + dir], 0) < 2) __builtin_amdgcn_s_sleep(8);
      }
      __syncthreads();
    }
    float xg_cur = *xp;

    for (int s = 0; s < TT; ++s) {
      if ((s & 15) == 0 && s) {
        if (tid < 9) {
          int p0 = (dir ? (TT - 1 - s) : s) >> 1;
          int p = dir ? (p0 - tid) : (p0 + tid);
          p = p < 0 ? 0 : (p > 255 ? 255 : p);
          while (atomicAdd(&flags[p * 2 + dir], 0) < 2) __builtin_amdgcn_s_sleep(8);
        }
        __syncthreads();
      }
      const int t = dir ? (TT - 1 - s) : s;
      float xg_nxt = 0.f;
      if (s + 1 < TT) { xp += stepoff; xg_nxt = *xp; }

      float a0 = xg_cur, a1 = 0.f, a2 = 0.f, a3 = 0.f;
#pragma unroll
      for (int i = 0; i < 32; ++i) {
        const float4 hv = *(const float4*)(hs + 4 * i);   // uniform broadcast
        a0 = fmaf(w[i].x, hv.x, a0);
        a1 = fmaf(w[i].y, hv.y, a1);
        a2 = fmaf(w[i].z, hv.z, a2);
        a3 = fmaf(w[i].w, hv.w, a3);
      }
      const float acc = (a0 + a1) + (a2 + a3);
      const float act = (gate == 2) ? tanhf(acc) : (1.f / (1.f + expf(-acc)));
      gs[j] = act;
      __syncthreads();           // gs ready; all reads of hs complete
      if (j < 128) {
        float ig = gs[j], fg = gs[128 + j], gg = gs[256 + j], og = gs[384 + j];
        c = fmaf(fg, c, ig * gg);
        float h = og * tanhf(c);
        hs[j] = h;
        HS[((long)t * 32 + b) * 256 + dir * 128 + j] = h;
      }
      __syncthreads();           // hs ready for next step
      xg_cur = xg_nxt;
    }
  }
}

// ---------------------------------------------------------------------------
// K3: feats. FE layout [t][k][b]. (unchanged)
// ---------------------------------------------------------------------------
__global__ __launch_bounds__(64) void k3_feats(const float* __restrict__ HS,
    const float* __restrict__ Wout, const float* __restrict__ bout,
    float* __restrict__ FE)
{
  __shared__ __align__(16) float ws[12 * 256];
  __shared__ float bs[12];
  const int tid = threadIdx.x;
  for (int i = tid; i < 768; i += 64)
    ((float4*)ws)[i] = ((const float4*)Wout)[i];
  if (tid < 12) bs[tid] = bout[tid];
  __syncthreads();
  const long row = (long)blockIdx.x * 64 + tid;
  const float4* hp = (const float4*)(HS + row * 256);
  float acc[12];
#pragma unroll
  for (int k = 0; k < 12; ++k) acc[k] = bs[k];
  for (int e4 = 0; e4 < 64; ++e4) {
    float4 hv = hp[e4];
#pragma unroll
    for (int k = 0; k < 12; ++k) {
      const float4 wv = *(const float4*)&ws[k * 256 + e4 * 4];
      acc[k] = fmaf(hv.x, wv.x, acc[k]);
      acc[k] = fmaf(hv.y, wv.y, acc[k]);
      acc[k] = fmaf(hv.z, wv.z, acc[k]);
      acc[k] = fmaf(hv.w, wv.w, acc[k]);
    }
  }
  const int t = (int)(row >> 5), b = (int)(row & 31);
#pragma unroll
  for (int k = 0; k < 12; ++k) FE[((long)t * 12 + k) * 32 + b] = acc[k];
}

// ---------------------------------------------------------------------------
// K4: Viterbi, single-wave WGs (unchanged from round 11 -- proven: rest of
// pipeline 338 -> 309us vs the 6-wave barriered version).
// ---------------------------------------------------------------------------
__global__ __launch_bounds__(64) void k4_viterbi(const float* __restrict__ FE,
    const float* __restrict__ trans, int* __restrict__ out)
{
  __shared__ unsigned char ptrl[TT * 48];       // [t][bsub][12]  24576 B
  __shared__ __align__(16) float sc[2][4][12];  // double-buffered scores
  const int l = threadIdx.x;
  const int bsub = l / 12;                      // 0..5; active if <4
  const int nxt = l % 12;
  const bool act = (bsub < 4);
  const int bs = act ? bsub : 0;                // clamped for reads
  const int b = blockIdx.x * 4 + bs;

  float tr[12], stopv[12];
#pragma unroll
  for (int p = 0; p < 12; ++p) tr[p] = trans[nxt * 12 + p];
#pragma unroll
  for (int p = 0; p < 12; ++p) stopv[p] = trans[10 * 12 + p];   // STOP=10

  if (act) sc[0][bsub][nxt] = (nxt == 9) ? 0.f : NEGF;          // START=9
  __syncthreads();

  float fnext = FE[nxt * 32 + b];
  for (int t = 0; t < TT; ++t) {
    const int cur = t & 1;
    const float feat = fnext;
    if (t + 1 < TT) fnext = FE[((t + 1) * 12 + nxt) * 32 + b];

    float sp[12];
    *(float4*)&sp[0] = *(const float4*)&sc[cur][bs][0];
    *(float4*)&sp[4] = *(const float4*)&sc[cur][bs][4];
    *(float4*)&sp[8] = *(const float4*)&sc[cur][bs][8];
    float best = -1e30f; int arg = 0;
#pragma unroll
    for (int p = 0; p < 12; ++p) {
      const float v = sp[p] + tr[p];
      if (v > best) { best = v; arg = p; }
    }
    if (act) {
      sc[cur ^ 1][bsub][nxt] = best + feat;     // write other buffer: no WAR
      ptrl[t * 48 + bsub * 12 + nxt] = (unsigned char)arg;
    }
    __syncthreads();                            // single wave: near-free
  }

  float best = -1e30f; int arg = 0;
#pragma unroll
  for (int p = 0; p < 12; ++p) {
    const float v = sc[0][bs][p] + stopv[p];
    if (v > best) { best = v; arg = p; }
  }
  if (act && nxt == 0) {
    int tag = arg;
    for (int t = TT - 1; t >= 0; --t) {
      out[b * TT + t] = tag;
      if (t) tag = ptrl[t * 48 + bsub * 12 + tag];
    }
  }
}

// ---------------------------------------------------------------------------
extern "C" void kernel_launch(void* const* d_in, const int* in_sizes, int n_in,
                              void* d_out, int out_size, void* d_ws, size_t ws_size,
                              hipStream_t stream)
{
  const int* sent = (const int*)d_in[0];
  const float* h0 = (const float*)d_in[1];
  const float* c0 = (const float*)d_in[2];
  const float* embed = (const float*)d_in[3];
  const float* Wif = (const float*)d_in[4];
  const float* Whf = (const float*)d_in[5];
  const float* bf = (const float*)d_in[6];
  const float* Wir = (const float*)d_in[7];
  const float* Whr = (const float*)d_in[8];
  const float* br = (const float*)d_in[9];
  const float* Wout = (const float*)d_in[10];
  const float* bout = (const float*)d_in[11];
  const float* trans = (const float*)d_in[12];

  char* ws = (char*)d_ws;
  float* XG = (float*)ws;                                   // 67,108,864 B
  float* HS = (float*)(ws + 67108864);                      // 16,777,216 B
  float* FE = (float*)(ws + 67108864 + 16777216);           //    786,432 B
  int* flags = (int*)(ws + 67108864 + 16777216 + 786432);   //      2,048 B
  int* out = (int*)d_out;

  // flags must be zero every call (harness poisons ws once, never restores)
  hipMemsetAsync(flags, 0, 512 * sizeof(int), stream);

  hipLaunchKernelGGL(k12_fused, dim3(256), dim3(512), 0, stream,
                     sent, embed, Wif, bf, Wir, br, Whf, Whr, h0, c0,
                     XG, HS, flags);
  hipLaunchKernelGGL(k3_feats, dim3(256), dim3(64), 0, stream,
                     HS, Wout, bout, FE);
  hipLaunchKernelGGL(k4_viterbi, dim3(8), dim3(64), 0, stream,
                     FE, trans, out);
}